// Round 9
// baseline (259.401 us; speedup 1.0000x reference)
//
#include <hip/hip_runtime.h>
#include <hip/hip_bf16.h>
#include <stdint.h>

typedef unsigned short u16;
typedef unsigned int u32;

using bf16x8 = __attribute__((ext_vector_type(8))) __bf16;  // 4 VGPRs: MFMA A/B operand
using f32x4  = __attribute__((ext_vector_type(4))) float;   // MFMA C/D operand

#define AS1 __attribute__((address_space(1)))
#define AS3 __attribute__((address_space(3)))

// fp32 -> bf16 round-to-nearest-even
__device__ __forceinline__ u16 f2bf(float x) {
  u32 u = __float_as_uint(x);
  u = (u + 0x7FFFu + ((u >> 16) & 1u)) >> 16;
  return (u16)u;
}
__device__ __forceinline__ float bf2f(u32 bits) { return __uint_as_float(bits << 16); }

// async global->LDS, 16B per lane. LDS dest = wave-uniform base + lane*16.
__device__ __forceinline__ void gload16(const void* g, void* l) {
  __builtin_amdgcn_global_load_lds((AS1 void*)(const_cast<void*>(g)),
                                   (AS3 void*)l, 16, 0, 0);
}

// load 16 contiguous bf16 (32B, aligned) into 16 floats
__device__ __forceinline__ void load16bf(const u16* p, float* f) {
  uint4 a = *(const uint4*)(p);
  uint4 b = *(const uint4*)(p + 8);
  u32 v[8] = {a.x, a.y, a.z, a.w, b.x, b.y, b.z, b.w};
#pragma unroll
  for (int i = 0; i < 8; ++i) {
    f[2 * i]     = __uint_as_float(v[i] << 16);
    f[2 * i + 1] = __uint_as_float(v[i] & 0xFFFF0000u);
  }
}

// convert 8 fp32 (aligned) -> 8 bf16, one uint4 store (16B/lane)
__device__ __forceinline__ void cvt8(const float* __restrict__ s,
                                     u16* __restrict__ d, size_t i,
                                     float scale) {
  float4 a = *(const float4*)(s + i);
  float4 b = *(const float4*)(s + i + 4);
  uint4 o;
  o.x = (u32)f2bf(a.x * scale) | ((u32)f2bf(a.y * scale) << 16);
  o.y = (u32)f2bf(a.z * scale) | ((u32)f2bf(a.w * scale) << 16);
  o.z = (u32)f2bf(b.x * scale) | ((u32)f2bf(b.y * scale) << 16);
  o.w = (u32)f2bf(b.z * scale) | ((u32)f2bf(b.w * scale) << 16);
  *(uint4*)(d + i) = o;
}

// ---------------------------------------------------------------------------
// k_prep = cvt (bf16 repack, 8 elems/thread, LORA_SCALE folded) + router.
// Blocks [0, 5760): 8-elem vectorized convert of 11,796,480 weight elements.
// Blocks [5760, 6272): router, 4 tokens/block (1 wave each).
// ---------------------------------------------------------------------------
__global__ __launch_bounds__(256) void k_prep(
    const float* __restrict__ hs, const float* __restrict__ gate,
    const float* __restrict__ W1, const float* __restrict__ W2,
    const float* __restrict__ A1, const float* __restrict__ B1,
    const float* __restrict__ B2, const float* __restrict__ A2,
    u16* __restrict__ Xbf, u16* __restrict__ W1bf, u16* __restrict__ W2bf,
    u16* __restrict__ A1bf, u16* __restrict__ B1s, u16* __restrict__ B2s,
    u16* __restrict__ A2bf, int* __restrict__ sel, float* __restrict__ wgt) {
  if (blockIdx.x < 5760) {
    size_t i = ((size_t)blockIdx.x * 256 + threadIdx.x) * 8;
    if (i < 2097152) { cvt8(hs, Xbf, i, 1.f); return; }
    i -= 2097152;
    if (i < 4194304) { cvt8(W1, W1bf, i, 1.f); return; }
    i -= 4194304;
    if (i < 4194304) { cvt8(W2, W2bf, i, 1.f); return; }
    i -= 4194304;
    if (i < 131072) { cvt8(A1, A1bf, i, 1.f); return; }
    i -= 131072;
    if (i < 524288) { cvt8(B1, B1s, i, 2.0f); return; }   // [E,H,R], LORA_SCALE
    i -= 524288;
    if (i < 131072) { cvt8(B2, B2s, i, 2.0f); return; }   // [E,D,R], LORA_SCALE
    i -= 131072;
    cvt8(A2, A2bf, i, 1.f);                               // [E,R,H] plain
    return;
  }
  // ---- router: top-2 renormalized softmax = sigmoid(l0-l1); no atomics ----
  const int lane = threadIdx.x & 63;
  const int wv = threadIdx.x >> 6;
  const int t = (blockIdx.x - 5760) * 4 + wv;
  const float* xp = hs + (size_t)t * 1024 + lane * 16;
  float4 xv[4];
#pragma unroll
  for (int i = 0; i < 4; ++i) xv[i] = *(const float4*)(xp + i * 4);
  float acc[8];
#pragma unroll
  for (int e = 0; e < 8; ++e) {
    const float* gp = gate + e * 1024 + lane * 16;
    float s = 0.f;
#pragma unroll
    for (int i = 0; i < 4; ++i) {
      float4 g = *(const float4*)(gp + i * 4);
      s += xv[i].x * g.x + xv[i].y * g.y + xv[i].z * g.z + xv[i].w * g.w;
    }
    acc[e] = s;
  }
#pragma unroll
  for (int e = 0; e < 8; ++e)
    for (int off = 32; off > 0; off >>= 1) acc[e] += __shfl_xor(acc[e], off);
  if (lane == 0) {
    int e0 = 0; float l0 = acc[0];
#pragma unroll
    for (int e = 1; e < 8; ++e) if (acc[e] > l0) { l0 = acc[e]; e0 = e; }
    int e1 = (e0 == 0) ? 1 : 0; float l1 = acc[e1];
#pragma unroll
    for (int e = 0; e < 8; ++e)
      if (e != e0 && acc[e] > l1) { l1 = acc[e]; e1 = e; }
    float p = 1.f / (1.f + __expf(l1 - l0));
    sel[2 * t] = e0; sel[2 * t + 1] = e1;
    wgt[2 * t] = p;  wgt[2 * t + 1] = 1.f - p;
  }
}

// ---------------------------------------------------------------------------
// bf16 GEMM, C[m,n] = sum_k A[m,k]*B[n,k].
// 128x128 tile, BK=64, 256 threads, 16x16x32 MFMA, global_load_lds w=16,
// XOR chunk swizzle. blockIdx.z = split-K slice; bias added on slice 0 only.
// aux_mode==1: block (0,33,0) runs the 8-bin expert sort (rides GEMM1).
// aux_mode==2: blockIdx.y>=8 runs T-GEMM blocks: Tp[zz][p,:] = Zw[p, k-split
//   zz of 256] @ A2[e]^T via MFMA (rides GEMM2).
// ---------------------------------------------------------------------------
__global__ __launch_bounds__(256, 2) void gemm_bt(
    const u16* __restrict__ A, const u16* __restrict__ B, void* __restrict__ Cv,
    int K, int ldc, int Ksub, size_t Cstride_elems, int outbf,
    const float* __restrict__ bias, int bias_n, int aux_mode,
    const int* __restrict__ sel, int* __restrict__ rows,
    int* __restrict__ tile_expert, const u16* __restrict__ Zw,
    const u16* __restrict__ A2bf, float* __restrict__ Tp) {
  __shared__ alignas(16) u16 lsA[128 * 64];
  __shared__ alignas(16) u16 lsB[128 * 64];

  if (aux_mode == 1 && blockIdx.y == 33) {
    if (blockIdx.x != 0 || blockIdx.z != 0) return;
    // ---- deterministic 8-bin sort of 4096 (token,slot) pairs, 4 waves ----
    int* wavehist = (int*)lsA;   // [4][8]
    int* stot = wavehist + 32;   // [8]
    int* waveoff = stot + 8;     // [4][8]
    const int tid = threadIdx.x;
    const int lane = tid & 63, w = tid >> 6;
    for (int i = tid; i < 4608; i += 256) rows[i] = -1;
    int ev[16], rk[16];
    int wc[8] = {};
    const unsigned long long ltmask = (1ull << lane) - 1;
#pragma unroll
    for (int j = 0; j < 16; ++j) {
      ev[j] = sel[w * 1024 + j * 64 + lane];
#pragma unroll
      for (int ex = 0; ex < 8; ++ex) {
        unsigned long long m = __ballot(ev[j] == ex);
        if (ev[j] == ex) rk[j] = wc[ex] + __popcll(m & ltmask);
        wc[ex] += __popcll(m);
      }
    }
#pragma unroll
    for (int ex = 0; ex < 8; ++ex)
      if (lane == ex) wavehist[w * 8 + ex] = wc[ex];  // wc wave-uniform
    __syncthreads();
    if (tid < 8) {
      int s = 0;
      for (int ww = 0; ww < 4; ++ww) s += wavehist[ww * 8 + tid];
      stot[tid] = s;
    }
    __syncthreads();
    if (tid < 32) {
      int ww = tid >> 3, ex = tid & 7;
      int base = 0;
      for (int e2 = 0; e2 < ex; ++e2) base += (stot[e2] + 63) & ~63;
      for (int w2 = 0; w2 < ww; ++w2) base += wavehist[w2 * 8 + ex];
      waveoff[ww * 8 + ex] = base;
    } else if (tid < 104) {
      int tt = tid - 32;
      int pos = tt * 64, acc2 = 0, e2 = 0;
      while (e2 < 7) {
        int na = acc2 + ((stot[e2] + 63) & ~63);
        if (pos < na) break;
        acc2 = na; ++e2;
      }
      tile_expert[tt] = e2;
    }
    __syncthreads();
#pragma unroll
    for (int j = 0; j < 16; ++j)
      rows[waveoff[w * 8 + ev[j]] + rk[j]] = w * 1024 + j * 64 + lane;
    return;
  }

  if (aux_mode == 2 && blockIdx.y >= 8) {
    // ---- T-GEMM: tile of 64 sorted rows, zz = k-split of 256 (16 slices) ----
    const int idx = (blockIdx.y - 8) * 16 + blockIdx.x;  // 0..143
    const int tile = idx >> 1;                            // 0..71
    const int zz = (idx & 1) * 8 + blockIdx.z;            // 0..15
    const int k0 = zz * 256;
    const int tid = threadIdx.x;
    const int lane = tid & 63, wv = tid >> 6;
    const int fr = lane & 15, fq = lane >> 4;
    const int e = tile_expert[tile];
    int p = rows[tile * 64 + wv * 16 + fr];
    int p0 = p < 0 ? 0 : p;
    const u16* zp = Zw + (size_t)p0 * 4096 + k0 + fq * 8;
    const u16* ap = A2bf + (size_t)e * 65536 + (size_t)fr * 4096 + k0 + fq * 8;
    f32x4 acc = {};
#pragma unroll
    for (int k = 0; k < 256; k += 32) {
      bf16x8 av = *(const bf16x8*)(zp + k);
      bf16x8 bv = *(const bf16x8*)(ap + k);
      acc = __builtin_amdgcn_mfma_f32_16x16x32_bf16(av, bv, acc, 0, 0, 0);
    }
#pragma unroll
    for (int r = 0; r < 4; ++r) {
      int pm = rows[tile * 64 + wv * 16 + fq * 4 + r];
      if (pm >= 0) Tp[(size_t)zz * 65536 + pm * 16 + fr] = acc[r];
    }
    return;
  }

  const int tid = threadIdx.x;
  const int lane = tid & 63;
  const int w = tid >> 6;
  const int m0 = blockIdx.x * 128;
  const int n0 = blockIdx.y * 128;
  const int z = blockIdx.z;
  const int wm = w & 1, wn = w >> 1;

  f32x4 acc[4][4] = {};

  const int sr = lane >> 3;
  const int sc = lane & 7;
  const int cg = sc ^ sr;
  const u16* Ag = A + (size_t)(m0 + w * 32 + sr) * K + (size_t)z * Ksub + cg * 8;
  const u16* Bg = B + (size_t)(n0 + w * 32 + sr) * K + (size_t)z * Ksub + cg * 8;
  u16* lA = lsA + w * 2048;
  u16* lB = lsB + w * 2048;

  const int fr = lane & 15;
  const int fq = lane >> 4;

  for (int kt = 0; kt < Ksub; kt += 64) {
#pragma unroll
    for (int j = 0; j < 4; ++j) {
      gload16(Ag + (size_t)j * 8 * K, lA + j * 512);
      gload16(Bg + (size_t)j * 8 * K, lB + j * 512);
    }
    Ag += 64; Bg += 64;
    __syncthreads();
#pragma unroll
    for (int s = 0; s < 2; ++s) {
      const int cl = (s * 4 + fq) ^ (fr & 7);
      bf16x8 av[4], bv[4];
#pragma unroll
      for (int i = 0; i < 4; ++i)
        av[i] = *(const bf16x8*)&lsA[(wm * 64 + i * 16 + fr) * 64 + cl * 8];
#pragma unroll
      for (int j = 0; j < 4; ++j)
        bv[j] = *(const bf16x8*)&lsB[(wn * 64 + j * 16 + fr) * 64 + cl * 8];
#pragma unroll
      for (int i = 0; i < 4; ++i)
#pragma unroll
        for (int j = 0; j < 4; ++j)
          acc[i][j] = __builtin_amdgcn_mfma_f32_16x16x32_bf16(av[i], bv[j], acc[i][j], 0, 0, 0);
    }
    __syncthreads();
  }

  const size_t zoff = (size_t)z * Cstride_elems;
  if (outbf) {
    u16* Co = (u16*)Cv + zoff;
#pragma unroll
    for (int i = 0; i < 4; ++i)
#pragma unroll
      for (int j = 0; j < 4; ++j)
#pragma unroll
        for (int r = 0; r < 4; ++r) {
          int m = m0 + wm * 64 + i * 16 + fq * 4 + r;
          int n = n0 + wn * 64 + j * 16 + fr;
          float bv2 = (bias && n < bias_n && z == 0) ? bias[n] : 0.f;
          Co[(size_t)m * ldc + n] = f2bf(acc[i][j][r] + bv2);
        }
  } else {
    float* Co = (float*)Cv + zoff;
#pragma unroll
    for (int i = 0; i < 4; ++i)
#pragma unroll
      for (int j = 0; j < 4; ++j)
#pragma unroll
        for (int r = 0; r < 4; ++r) {
          int m = m0 + wm * 64 + i * 16 + fq * 4 + r;
          int n = n0 + wn * 64 + j * 16 + fr;
          Co[(size_t)m * ldc + n] = acc[i][j][r];
        }
  }
}

// ---------------------------------------------------------------------------
// Expert-sorted LoRA1 + silu. Grid (288, 4) = 1152 blocks:
// blockIdx.x = tile*4 + rsub -> rows [tile*64+rsub*16, +16); 4 h per thread
// (uint2), h0 = blockIdx.y*1024 + tid*4. Serial row loop = 16 iterations.
// C1p = two bf16 split-K slices of [2048,4224] (cols 0..4095 = x@W1^T (+b1 in
// slice 0), 4096..4223 = x@A1_all^T); this kernel sums the slices on read.
// Zw[p,h] = w_p*silu(C1 + LX·B1s[e][h]).
// ---------------------------------------------------------------------------
__global__ __launch_bounds__(256) void k_lora1(
    const u16* __restrict__ C1p, const u16* __restrict__ B1s,
    const int* __restrict__ rows, const int* __restrict__ tile_expert,
    const float* __restrict__ wgt, u16* __restrict__ Zw) {
  const int tile = blockIdx.x >> 2;
  const int rsub = blockIdx.x & 3;
  const int tid = threadIdx.x;
  const int h0 = blockIdx.y * 1024 + tid * 4;
  const int e = tile_expert[tile];
  const u16* C1b = C1p + 8650752;  // slice 1
  __shared__ int sp[16];
  __shared__ float sw[16];
  __shared__ alignas(16) float slx[16][16];
  if (tid < 16) {
    int p = rows[tile * 64 + rsub * 16 + tid];
    sp[tid] = p;
    sw[tid] = (p >= 0) ? wgt[p] : 0.f;
  }
  __syncthreads();
  {
    int i = tid >> 4, r = tid & 15;
    int p = sp[i];
    size_t ix = (size_t)(p >> 1) * 4224 + 4096 + e * 16 + r;
    slx[i][r] = (p >= 0) ? (bf2f(C1p[ix]) + bf2f(C1b[ix])) : 0.f;
  }
  float bw[4][16];
#pragma unroll
  for (int j = 0; j < 4; ++j)
    load16bf(B1s + (size_t)e * 65536 + (size_t)(h0 + j) * 16, bw[j]);
  __syncthreads();
#pragma unroll 2
  for (int i = 0; i < 16; ++i) {
    int p = sp[i];
    if (p < 0) continue;  // block-uniform
    int t = p >> 1;
    uint2 c0 = *(const uint2*)&C1p[(size_t)t * 4224 + h0];
    uint2 c1 = *(const uint2*)&C1b[(size_t)t * 4224 + h0];
    float c[4];
    c[0] = __uint_as_float(c0.x << 16) + __uint_as_float(c1.x << 16);
    c[1] = __uint_as_float(c0.x & 0xFFFF0000u) + __uint_as_float(c1.x & 0xFFFF0000u);
    c[2] = __uint_as_float(c0.y << 16) + __uint_as_float(c1.y << 16);
    c[3] = __uint_as_float(c0.y & 0xFFFF0000u) + __uint_as_float(c1.y & 0xFFFF0000u);
    float d[4] = {0.f, 0.f, 0.f, 0.f};
#pragma unroll
    for (int rr = 0; rr < 4; ++rr) {
      float4 v = *(const float4*)&slx[i][rr * 4];  // LDS broadcast
#pragma unroll
      for (int j = 0; j < 4; ++j)
        d[j] += v.x * bw[j][rr * 4] + v.y * bw[j][rr * 4 + 1] +
                v.z * bw[j][rr * 4 + 2] + v.w * bw[j][rr * 4 + 3];
    }
    float wv = sw[i];
    u32 o[2];
#pragma unroll
    for (int jj = 0; jj < 2; ++jj) {
      float z0 = c[2 * jj] + d[2 * jj];
      float z1 = c[2 * jj + 1] + d[2 * jj + 1];
      float s0 = wv * z0 / (1.f + __expf(-z0));
      float s1 = wv * z1 / (1.f + __expf(-z1));
      o[jj] = (u32)f2bf(s0) | ((u32)f2bf(s1) << 16);
    }
    *(uint2*)&Zw[(size_t)p * 4096 + h0] = make_uint2(o[0], o[1]);
  }
}

// ---------------------------------------------------------------------------
// am[t,h] = Zw[2t,h] + Zw[2t+1,h]  (bf16, vectorized x8)
// ---------------------------------------------------------------------------
__global__ __launch_bounds__(256) void k_am(const u16* __restrict__ Zw,
                                            u16* __restrict__ am) {
  int gid = blockIdx.x * 256 + threadIdx.x;
  int t = gid >> 9;
  int hh = (gid & 511) * 8;
  const u16* z0 = Zw + (size_t)(2 * t) * 4096 + hh;
  const u16* z1 = Zw + (size_t)(2 * t + 1) * 4096 + hh;
  uint4 a = *(const uint4*)z0;
  uint4 b = *(const uint4*)z1;
  u32 va[4] = {a.x, a.y, a.z, a.w};
  u32 vb[4] = {b.x, b.y, b.z, b.w};
  u32 out[4];
#pragma unroll
  for (int i = 0; i < 4; ++i) {
    float lo = __uint_as_float(va[i] << 16) + __uint_as_float(vb[i] << 16);
    float hi = __uint_as_float(va[i] & 0xFFFF0000u) + __uint_as_float(vb[i] & 0xFFFF0000u);
    out[i] = (u32)f2bf(lo) | ((u32)f2bf(hi) << 16);
  }
  *(uint4*)(am + (size_t)t * 4096 + hh) = *(uint4*)out;
}

// ---------------------------------------------------------------------------
// One block per token: reduce Tp over 16 z-slices into LDS, then
// out[t,d] = sum_{z<8} F2p[z][t,d] (bf16) + b2[d] + Ts0·B2s[e0][d] + Ts1·B2s[e1][d].
// 4 d per thread.
// ---------------------------------------------------------------------------
__global__ __launch_bounds__(256) void k_final(
    const u16* __restrict__ F2p, const float* __restrict__ b2,
    const u16* __restrict__ B2s, const float* __restrict__ Tp,
    const int* __restrict__ sel, float* __restrict__ out) {
  const int t = blockIdx.x;
  const int tid = threadIdx.x;
  __shared__ float Ts[32];  // [pair 2][r 16]
  if (tid < 32) {
    int p = 2 * t + (tid >> 4);
    int r = tid & 15;
    float s = 0.f;
#pragma unroll
    for (int z = 0; z < 16; ++z) s += Tp[(size_t)z * 65536 + p * 16 + r];
    Ts[tid] = s;
  }
  __syncthreads();
  const int e0 = sel[2 * t], e1 = sel[2 * t + 1];
  const int d0 = tid * 4;
  const size_t base = (size_t)t * 1024 + d0;
  float sum[4];
  {
    float4 bb = *(const float4*)&b2[d0];
    sum[0] = bb.x; sum[1] = bb.y; sum[2] = bb.z; sum[3] = bb.w;
  }
#pragma unroll
  for (int z = 0; z < 8; ++z) {
    uint2 q = *(const uint2*)&F2p[(size_t)z * 2097152 + base];
    sum[0] += __uint_as_float(q.x << 16);
    sum[1] += __uint_as_float(q.x & 0xFFFF0000u);
    sum[2] += __uint_as_float(q.y << 16);
    sum[3] += __uint_as_float(q.y & 0xFFFF0000u);
  }
#pragma unroll
  for (int j = 0; j < 4; ++j) {
    int d = d0 + j;
    float f0[16], f1[16];
    load16bf(B2s + (size_t)e0 * 16384 + d * 16, f0);
    load16bf(B2s + (size_t)e1 * 16384 + d * 16, f1);
#pragma unroll
    for (int r = 0; r < 16; ++r)
      sum[j] += Ts[r] * f0[r] + Ts[16 + r] * f1[r];
  }
  float4 o = {sum[0], sum[1], sum[2], sum[3]};
  *(float4*)&out[base] = o;
}

// ---------------------------------------------------------------------------
extern "C" void kernel_launch(void* const* d_in, const int* in_sizes, int n_in,
                              void* d_out, int out_size, void* d_ws, size_t ws_size,
                              hipStream_t stream) {
  const float* hs   = (const float*)d_in[0];
  const float* gate = (const float*)d_in[1];
  const float* W1   = (const float*)d_in[2];
  const float* b1   = (const float*)d_in[3];
  const float* W2   = (const float*)d_in[4];
  const float* b2   = (const float*)d_in[5];
  const float* A1   = (const float*)d_in[6];
  const float* B1   = (const float*)d_in[7];
  const float* A2   = (const float*)d_in[8];
  const float* B2   = (const float*)d_in[9];

  char* ws = (char*)d_ws;
  size_t off = 0;
  auto alloc = [&](size_t bytes) -> void* {
    void* p = ws + off;
    off += (bytes + 255) & ~(size_t)255;
    return p;
  };
  u16*   Xbf  = (u16*)alloc(2097152ull * 2);        // x bf16 [2048,1024]
  u16*   W1bf = (u16*)alloc(4194304ull * 2);        // [4096,1024]
  u16*   A1bf = (u16*)alloc(131072ull * 2);         // [128,1024] contiguous after W1bf
  u16*   W2bf = (u16*)alloc(4194304ull * 2);        // [1024,4096]
  u16*   B1s  = (u16*)alloc(524288ull * 2);         // 2*B1 [E,4096,16]
  u16*   B2s  = (u16*)alloc(131072ull * 2);         // 2*B2 [E,1024,16]
  u16*   A2bf = (u16*)alloc(524288ull * 2);         // A2 [E,16,4096] bf16
  u16*   C1p  = (u16*)alloc(2ull * 8650752 * 2);    // 2 split-K slices [2048,4224] (34.6MB)
  u16*   F2p  = C1p;                                // ALIAS: C1p dead after k_lora1
  u16*   am   = (u16*)alloc(2048ull * 4096 * 2);    // Zw[2t]+Zw[2t+1]
  u16*   Zw   = (u16*)alloc(4096ull * 4096 * 2);    // w_p*silu per pair (32MB)
  float* Tp   = (float*)alloc(16ull * 65536 * 4);   // 16 T k-split partials (4MB)
  int*   sel  = (int*)alloc(2048ull * 2 * 4);
  float* wgt  = (float*)alloc(2048ull * 2 * 4);
  int*   rows = (int*)alloc(4608 * 4);
  int*   tile_expert = (int*)alloc(72 * 4);

  // 1: cvt (8 elems/thread) + router
  k_prep<<<6272, 256, 0, stream>>>(hs, gate, W1, W2, A1, B1, B2, A2,
                                   Xbf, W1bf, W2bf, A1bf, B1s, B2s, A2bf,
                                   sel, wgt);
  // 2: C1p[z] = X @ [W1|A1_all]^T split-K=2 (+b1 on n<4096, slice 0),
  //    M=2048 N=4224 K=1024; sort rides as (0,33,0)
  gemm_bt<<<dim3(16, 34, 2), 256, 0, stream>>>(
      Xbf, W1bf, (void*)C1p, 1024, 4224, 512, 8650752, 1, b1, 4096,
      1, sel, rows, tile_expert, nullptr, nullptr, nullptr);
  // 3: Zw = w*silu(sum C1p + LoRA1), 1152 blocks
  k_lora1<<<dim3(288, 4), 256, 0, stream>>>(C1p, B1s, rows, tile_expert, wgt, Zw);
  // 4: am = pair-sum of Zw (pure streaming)
  k_am<<<4096, 256, 0, stream>>>(Zw, am);
  // 5: F2p[z] = am @ W2^T (split-K=8, bf16 out), M=2048 N=1024 K=4096;
  //    T-GEMM rides as y in [8,17): Tp[zz] = Zw @ A2^T (16 k-slices)
  gemm_bt<<<dim3(16, 17, 8), 256, 0, stream>>>(
      am, W2bf, (void*)F2p, 4096, 1024, 512, 2097152, 1, nullptr, 0,
      2, nullptr, rows, tile_expert, Zw, A2bf, Tp);
  // 6: out = sum F2p + b2 + (reduced Tp)·B2^T
  k_final<<<2048, 256, 0, stream>>>(F2p, b2, B2s, Tp, sel, (float*)d_out);
}

// Round 10
// 228.807 us; speedup vs baseline: 1.1337x; 1.1337x over previous
//
#include <hip/hip_runtime.h>
#include <hip/hip_bf16.h>
#include <stdint.h>

typedef unsigned short u16;
typedef unsigned int u32;

using bf16x8 = __attribute__((ext_vector_type(8))) __bf16;  // 4 VGPRs: MFMA A/B operand
using f32x4  = __attribute__((ext_vector_type(4))) float;   // MFMA C/D operand

#define AS1 __attribute__((address_space(1)))
#define AS3 __attribute__((address_space(3)))

// fp32 -> bf16 round-to-nearest-even
__device__ __forceinline__ u16 f2bf(float x) {
  u32 u = __float_as_uint(x);
  u = (u + 0x7FFFu + ((u >> 16) & 1u)) >> 16;
  return (u16)u;
}
__device__ __forceinline__ float bf2f(u32 bits) { return __uint_as_float(bits << 16); }

// async global->LDS, 16B per lane. LDS dest = wave-uniform base + lane*16.
__device__ __forceinline__ void gload16(const void* g, void* l) {
  __builtin_amdgcn_global_load_lds((AS1 void*)(const_cast<void*>(g)),
                                   (AS3 void*)l, 16, 0, 0);
}

// load 16 contiguous bf16 (32B, aligned) into 16 floats (global or LDS ptr)
__device__ __forceinline__ void load16bf(const u16* p, float* f) {
  uint4 a = *(const uint4*)(p);
  uint4 b = *(const uint4*)(p + 8);
  u32 v[8] = {a.x, a.y, a.z, a.w, b.x, b.y, b.z, b.w};
#pragma unroll
  for (int i = 0; i < 8; ++i) {
    f[2 * i]     = __uint_as_float(v[i] << 16);
    f[2 * i + 1] = __uint_as_float(v[i] & 0xFFFF0000u);
  }
}

// convert 8 fp32 (aligned) -> 8 bf16, one uint4 store (16B/lane)
__device__ __forceinline__ void cvt8(const float* __restrict__ s,
                                     u16* __restrict__ d, size_t i,
                                     float scale) {
  float4 a = *(const float4*)(s + i);
  float4 b = *(const float4*)(s + i + 4);
  uint4 o;
  o.x = (u32)f2bf(a.x * scale) | ((u32)f2bf(a.y * scale) << 16);
  o.y = (u32)f2bf(a.z * scale) | ((u32)f2bf(a.w * scale) << 16);
  o.z = (u32)f2bf(b.x * scale) | ((u32)f2bf(b.y * scale) << 16);
  o.w = (u32)f2bf(b.z * scale) | ((u32)f2bf(b.w * scale) << 16);
  *(uint4*)(d + i) = o;
}

__device__ __forceinline__ uint4 pack8(float4 a, float4 b) {
  uint4 o;
  o.x = (u32)f2bf(a.x) | ((u32)f2bf(a.y) << 16);
  o.y = (u32)f2bf(a.z) | ((u32)f2bf(a.w) << 16);
  o.z = (u32)f2bf(b.x) | ((u32)f2bf(b.y) << 16);
  o.w = (u32)f2bf(b.z) | ((u32)f2bf(b.w) << 16);
  return o;
}

// ---------------------------------------------------------------------------
// k_prep: blocks [0,5696) = vectorized bf16 repack (8 elems/thread, LORA_SCALE
// folded into B1,B2; A1 NOT converted - LX blocks handle it).
// Blocks [5696,6208) = router (4 tokens/block).
// Blocks [6208,6272) = LXp[z][t][o] = X[t,kslice z]@A1[o,kslice z]^T via MFMA
// with local fp32->bf16 conversion staging (self-contained; no dependency on
// the cvt blocks of this same launch).
// ---------------------------------------------------------------------------
__global__ __launch_bounds__(256) void k_prep(
    const float* __restrict__ hs, const float* __restrict__ gate,
    const float* __restrict__ W1, const float* __restrict__ W2,
    const float* __restrict__ A1, const float* __restrict__ B1,
    const float* __restrict__ B2, const float* __restrict__ A2,
    u16* __restrict__ Xbf, u16* __restrict__ W1bf, u16* __restrict__ W2bf,
    u16* __restrict__ B1s, u16* __restrict__ B2s, u16* __restrict__ A2bf,
    float* __restrict__ LXp, int* __restrict__ sel, float* __restrict__ wgt) {
  __shared__ alignas(16) u16 lsA[8192];
  __shared__ alignas(16) u16 lsB[8192];
  const int b = blockIdx.x;
  const int tid = threadIdx.x;
  if (b < 5696) {
    size_t i = ((size_t)b * 256 + tid) * 8;
    if (i < 2097152) { cvt8(hs, Xbf, i, 1.f); return; }
    i -= 2097152;
    if (i < 4194304) { cvt8(W1, W1bf, i, 1.f); return; }
    i -= 4194304;
    if (i < 4194304) { cvt8(W2, W2bf, i, 1.f); return; }
    i -= 4194304;
    if (i < 524288) { cvt8(B1, B1s, i, 2.0f); return; }   // [E,H,R], LORA_SCALE
    i -= 524288;
    if (i < 131072) { cvt8(B2, B2s, i, 2.0f); return; }   // [E,D,R], LORA_SCALE
    i -= 131072;
    cvt8(A2, A2bf, i, 1.f);                               // [E,R,H] plain
    return;
  }
  const int lane = tid & 63;
  const int wv = tid >> 6;
  if (b < 6208) {
    // ---- router: top-2 renormalized softmax = sigmoid(l0-l1) ----
    const int t = (b - 5696) * 4 + wv;
    const float* xp = hs + (size_t)t * 1024 + lane * 16;
    float4 xv[4];
#pragma unroll
    for (int i = 0; i < 4; ++i) xv[i] = *(const float4*)(xp + i * 4);
    float acc[8];
#pragma unroll
    for (int e = 0; e < 8; ++e) {
      const float* gp = gate + e * 1024 + lane * 16;
      float s = 0.f;
#pragma unroll
      for (int i = 0; i < 4; ++i) {
        float4 g = *(const float4*)(gp + i * 4);
        s += xv[i].x * g.x + xv[i].y * g.y + xv[i].z * g.z + xv[i].w * g.w;
      }
      acc[e] = s;
    }
#pragma unroll
    for (int e = 0; e < 8; ++e)
      for (int off = 32; off > 0; off >>= 1) acc[e] += __shfl_xor(acc[e], off);
    if (lane == 0) {
      int e0 = 0; float l0 = acc[0];
#pragma unroll
      for (int e = 1; e < 8; ++e) if (acc[e] > l0) { l0 = acc[e]; e0 = e; }
      int e1 = (e0 == 0) ? 1 : 0; float l1 = acc[e1];
#pragma unroll
      for (int e = 0; e < 8; ++e)
        if (e != e0 && acc[e] > l1) { l1 = acc[e]; e1 = e; }
      float p = 1.f / (1.f + __expf(l1 - l0));
      sel[2 * t] = e0; sel[2 * t + 1] = e1;
      wgt[2 * t] = p;  wgt[2 * t + 1] = 1.f - p;
    }
    return;
  }
  // ---- LX blocks: 16 t-tiles x 4 k-slices of 256 ----
  const int idx = b - 6208;
  const int tt = idx >> 2, z = idx & 3;
  const int m0 = tt * 128;
  const int k00 = z * 256;
  const int w = wv;
  const int wm = w & 1, wn = w >> 1;
  const int sr = lane >> 3, sc = lane & 7, cg = sc ^ sr;
  const int fr = lane & 15, fq = lane >> 4;
  f32x4 acc[4][4] = {};
  for (int kt = 0; kt < 256; kt += 64) {
#pragma unroll
    for (int j = 0; j < 4; ++j) {
      int row = w * 32 + sr + j * 8;
      const float* xs = hs + (size_t)(m0 + row) * 1024 + k00 + kt + cg * 8;
      *(uint4*)&lsA[row * 64 + sc * 8] =
          pack8(*(const float4*)xs, *(const float4*)(xs + 4));
      const float* as2 = A1 + (size_t)row * 1024 + k00 + kt + cg * 8;
      *(uint4*)&lsB[row * 64 + sc * 8] =
          pack8(*(const float4*)as2, *(const float4*)(as2 + 4));
    }
    __syncthreads();
#pragma unroll
    for (int s = 0; s < 2; ++s) {
      const int cl = (s * 4 + fq) ^ (fr & 7);
      bf16x8 av[4], bv[4];
#pragma unroll
      for (int i = 0; i < 4; ++i)
        av[i] = *(const bf16x8*)&lsA[(wm * 64 + i * 16 + fr) * 64 + cl * 8];
#pragma unroll
      for (int j = 0; j < 4; ++j)
        bv[j] = *(const bf16x8*)&lsB[(wn * 64 + j * 16 + fr) * 64 + cl * 8];
#pragma unroll
      for (int i = 0; i < 4; ++i)
#pragma unroll
        for (int j = 0; j < 4; ++j)
          acc[i][j] = __builtin_amdgcn_mfma_f32_16x16x32_bf16(av[i], bv[j], acc[i][j], 0, 0, 0);
    }
    __syncthreads();
  }
  float* Co = LXp + (size_t)z * 262144;
#pragma unroll
  for (int i = 0; i < 4; ++i)
#pragma unroll
    for (int j = 0; j < 4; ++j)
#pragma unroll
      for (int r = 0; r < 4; ++r) {
        int m = m0 + wm * 64 + i * 16 + fq * 4 + r;
        int n = wn * 64 + j * 16 + fr;
        Co[(size_t)m * 128 + n] = acc[i][j][r];
      }
}

// ---------------------------------------------------------------------------
// bf16 GEMM 128x128 tile, BK=64, 256 thr, 16x16x32 MFMA, global_load_lds w=16,
// XOR chunk swizzle.
// mode==1 (GEMM1, X@W1^T, grid (16,33,1)):
//   y<32: fused epilogue -> Zw[2t],Zw[2t+1],am (LoRA1+silu+routing weight);
//   y==32 (x==0): 8-bin expert sort of 4096 pairs -> rows/tile_expert.
// mode==2 (GEMM2, am@W2^T split-K=4 bf16 partials, grid (16,17,4)):
//   y<8: gemm; y>=8: T-GEMM Tp[zz][p,:] = Zw[p, k-split zz of 512] @ A2[e]^T.
// ---------------------------------------------------------------------------
__global__ __launch_bounds__(256, 2) void gemm_bt(
    const u16* __restrict__ A, const u16* __restrict__ B, void* __restrict__ Cv,
    int K, int ldc, int Ksub, size_t Cstride_elems, int outbf,
    const float* __restrict__ bias, int mode,
    const int* __restrict__ sel, const float* __restrict__ wgt,
    int* __restrict__ rows, int* __restrict__ tile_expert,
    const float* __restrict__ LXp, const u16* __restrict__ B1s,
    u16* __restrict__ am, u16* __restrict__ Zw,
    const u16* __restrict__ A2bf, float* __restrict__ Tp) {
  __shared__ alignas(16) u16 lsAB[16384];
  __shared__ alignas(16) float lxs[128][32];
  __shared__ float wsh[256];
  __shared__ int ssh[256];
  u16* lsA = lsAB;
  u16* lsB = lsAB + 8192;
  const int tid = threadIdx.x;
  const int lane = tid & 63;
  const int w = tid >> 6;

  if (mode == 1 && blockIdx.y == 32) {
    if (blockIdx.x != 0) return;
    // ---- deterministic 8-bin sort of 4096 (token,slot) pairs, 4 waves ----
    int* wavehist = (int*)lsAB;  // [4][8]
    int* stot = wavehist + 32;   // [8]
    int* waveoff = stot + 8;     // [4][8]
    for (int i = tid; i < 4608; i += 256) rows[i] = -1;
    int ev[16], rk[16];
    int wc[8] = {};
    const unsigned long long ltmask = (1ull << lane) - 1;
#pragma unroll
    for (int j = 0; j < 16; ++j) {
      ev[j] = sel[w * 1024 + j * 64 + lane];
#pragma unroll
      for (int ex = 0; ex < 8; ++ex) {
        unsigned long long m = __ballot(ev[j] == ex);
        if (ev[j] == ex) rk[j] = wc[ex] + __popcll(m & ltmask);
        wc[ex] += __popcll(m);
      }
    }
#pragma unroll
    for (int ex = 0; ex < 8; ++ex)
      if (lane == ex) wavehist[w * 8 + ex] = wc[ex];  // wc wave-uniform
    __syncthreads();
    if (tid < 8) {
      int s = 0;
      for (int ww = 0; ww < 4; ++ww) s += wavehist[ww * 8 + tid];
      stot[tid] = s;
    }
    __syncthreads();
    if (tid < 32) {
      int ww = tid >> 3, ex = tid & 7;
      int base = 0;
      for (int e2 = 0; e2 < ex; ++e2) base += (stot[e2] + 63) & ~63;
      for (int w2 = 0; w2 < ww; ++w2) base += wavehist[w2 * 8 + ex];
      waveoff[ww * 8 + ex] = base;
    } else if (tid < 104) {
      int tt = tid - 32;
      int pos = tt * 64, acc2 = 0, e2 = 0;
      while (e2 < 7) {
        int na = acc2 + ((stot[e2] + 63) & ~63);
        if (pos < na) break;
        acc2 = na; ++e2;
      }
      tile_expert[tt] = e2;
    }
    __syncthreads();
#pragma unroll
    for (int j = 0; j < 16; ++j)
      rows[waveoff[w * 8 + ev[j]] + rk[j]] = w * 1024 + j * 64 + lane;
    return;
  }

  if (mode == 2 && blockIdx.y >= 8) {
    // ---- T-GEMM: tile of 64 sorted rows, zz = k-split of 512 (8 slices) ----
    const int idx = (blockIdx.y - 8) * 16 + blockIdx.x;  // 0..143
    const int tile = idx >> 1;                            // 0..71
    const int zz = (idx & 1) * 4 + blockIdx.z;            // 0..7
    const int k0 = zz * 512;
    const int fr = lane & 15, fq = lane >> 4;
    const int e = tile_expert[tile];
    int p = rows[tile * 64 + w * 16 + fr];
    int p0 = p < 0 ? 0 : p;
    const u16* zp = Zw + (size_t)p0 * 4096 + k0 + fq * 8;
    const u16* ap = A2bf + (size_t)e * 65536 + (size_t)fr * 4096 + k0 + fq * 8;
    f32x4 acc = {};
#pragma unroll
    for (int k = 0; k < 512; k += 32) {
      bf16x8 av = *(const bf16x8*)(zp + k);
      bf16x8 bv = *(const bf16x8*)(ap + k);
      acc = __builtin_amdgcn_mfma_f32_16x16x32_bf16(av, bv, acc, 0, 0, 0);
    }
#pragma unroll
    for (int r = 0; r < 4; ++r) {
      int pm = rows[tile * 64 + w * 16 + fq * 4 + r];
      if (pm >= 0) Tp[(size_t)zz * 65536 + pm * 16 + fr] = acc[r];
    }
    return;
  }

  const int m0 = blockIdx.x * 128;
  const int n0 = blockIdx.y * 128;
  const int z = blockIdx.z;
  const int wm = w & 1, wn = w >> 1;

  f32x4 acc[4][4] = {};

  const int sr = lane >> 3;
  const int sc = lane & 7;
  const int cg = sc ^ sr;
  const u16* Ag = A + (size_t)(m0 + w * 32 + sr) * K + (size_t)z * Ksub + cg * 8;
  const u16* Bg = B + (size_t)(n0 + w * 32 + sr) * K + (size_t)z * Ksub + cg * 8;
  u16* lA = lsA + w * 2048;
  u16* lB = lsB + w * 2048;

  const int fr = lane & 15;
  const int fq = lane >> 4;

  for (int kt = 0; kt < Ksub; kt += 64) {
#pragma unroll
    for (int j = 0; j < 4; ++j) {
      gload16(Ag + (size_t)j * 8 * K, lA + j * 512);
      gload16(Bg + (size_t)j * 8 * K, lB + j * 512);
    }
    Ag += 64; Bg += 64;
    __syncthreads();
#pragma unroll
    for (int s = 0; s < 2; ++s) {
      const int cl = (s * 4 + fq) ^ (fr & 7);
      bf16x8 av[4], bv[4];
#pragma unroll
      for (int i = 0; i < 4; ++i)
        av[i] = *(const bf16x8*)&lsA[(wm * 64 + i * 16 + fr) * 64 + cl * 8];
#pragma unroll
      for (int j = 0; j < 4; ++j)
        bv[j] = *(const bf16x8*)&lsB[(wn * 64 + j * 16 + fr) * 64 + cl * 8];
#pragma unroll
      for (int i = 0; i < 4; ++i)
#pragma unroll
        for (int j = 0; j < 4; ++j)
          acc[i][j] = __builtin_amdgcn_mfma_f32_16x16x32_bf16(av[i], bv[j], acc[i][j], 0, 0, 0);
    }
    __syncthreads();
  }

  if (mode == 1) {
    // ======== fused LoRA1 + silu + routing-weight epilogue ========
    // phase 1: sel/wgt -> LDS; B1s rows (all 8 experts, this n-range) -> lsAB
    {
      int mt2 = tid >> 1, slot = tid & 1;
      ssh[tid] = sel[(m0 + mt2) * 2 + slot];
      wsh[tid] = wgt[(m0 + mt2) * 2 + slot];
    }
#pragma unroll
    for (int q = 0; q < 8; ++q) {
      int idx2 = q * 2048 + tid * 8;      // e = idx2>>11, rem = hh*16+r0
      int e = idx2 >> 11, rem = idx2 & 2047;
      *(uint4*)&lsAB[idx2] =
          *(const uint4*)&B1s[(size_t)e * 65536 + (size_t)n0 * 16 + rem];
    }
    __syncthreads();
    // phase 2: LX rows (4 k-slices summed) for each (token, slot) -> lxs
    {
      int mt2 = tid >> 1, slot = tid & 1;
      int e = ssh[tid];
      const float* src = LXp + (size_t)(m0 + mt2) * 128 + e * 16;
#pragma unroll
      for (int q = 0; q < 4; ++q) {
        float4 v0 = *(const float4*)(src + q * 4);
        float4 v1 = *(const float4*)(src + 262144 + q * 4);
        float4 v2 = *(const float4*)(src + 524288 + q * 4);
        float4 v3 = *(const float4*)(src + 786432 + q * 4);
        float4 vv = {v0.x + v1.x + v2.x + v3.x, v0.y + v1.y + v2.y + v3.y,
                     v0.z + v1.z + v2.z + v3.z, v0.w + v1.w + v2.w + v3.w};
        *(float4*)&lxs[mt2][slot * 16 + q * 4] = vv;
      }
    }
    __syncthreads();
    // phase 3: per acc element compute both slots, store Zw x2 + am
    float b1v[4];
#pragma unroll
    for (int j = 0; j < 4; ++j) b1v[j] = bias[n0 + wn * 64 + j * 16 + fr];
#pragma unroll
    for (int i = 0; i < 4; ++i) {
#pragma unroll
      for (int r = 0; r < 4; ++r) {
        int mt2 = wm * 64 + i * 16 + fq * 4 + r;
        int t = m0 + mt2;
        int e0 = ssh[mt2 * 2], e1 = ssh[mt2 * 2 + 1];
        float w0 = wsh[mt2 * 2], w1 = wsh[mt2 * 2 + 1];
        float lx0[16], lx1[16];
#pragma unroll
        for (int q = 0; q < 4; ++q) {
          *(float4*)&lx0[q * 4] = *(const float4*)&lxs[mt2][q * 4];
          *(float4*)&lx1[q * 4] = *(const float4*)&lxs[mt2][16 + q * 4];
        }
#pragma unroll
        for (int j = 0; j < 4; ++j) {
          int nn = wn * 64 + j * 16 + fr;
          float c = acc[i][j][r] + b1v[j];
          float f0[16], f1[16];
          load16bf(&lsAB[e0 * 2048 + nn * 16], f0);
          load16bf(&lsAB[e1 * 2048 + nn * 16], f1);
          float d0 = 0.f, d1 = 0.f;
#pragma unroll
          for (int rr = 0; rr < 16; ++rr) {
            d0 += lx0[rr] * f0[rr];
            d1 += lx1[rr] * f1[rr];
          }
          float z0 = c + d0, z1 = c + d1;
          float s0 = w0 * z0 / (1.f + __expf(-z0));
          float s1 = w1 * z1 / (1.f + __expf(-z1));
          size_t go = (size_t)t * 4096 + n0 + nn;
          am[go] = f2bf(s0 + s1);
          Zw[(size_t)(2 * t) * 4096 + n0 + nn] = f2bf(s0);
          Zw[(size_t)(2 * t + 1) * 4096 + n0 + nn] = f2bf(s1);
        }
      }
    }
    return;
  }

  // standard C write (mode 2 gemm blocks)
  const size_t zoff = (size_t)z * Cstride_elems;
  if (outbf) {
    u16* Co = (u16*)Cv + zoff;
#pragma unroll
    for (int i = 0; i < 4; ++i)
#pragma unroll
      for (int j = 0; j < 4; ++j)
#pragma unroll
        for (int r = 0; r < 4; ++r) {
          int m = m0 + wm * 64 + i * 16 + fq * 4 + r;
          int n = n0 + wn * 64 + j * 16 + fr;
          float bv2 = bias ? bias[n] : 0.f;
          Co[(size_t)m * ldc + n] = f2bf(acc[i][j][r] + bv2);
        }
  } else {
    float* Co = (float*)Cv + zoff;
#pragma unroll
    for (int i = 0; i < 4; ++i)
#pragma unroll
      for (int j = 0; j < 4; ++j)
#pragma unroll
        for (int r = 0; r < 4; ++r) {
          int m = m0 + wm * 64 + i * 16 + fq * 4 + r;
          int n = n0 + wn * 64 + j * 16 + fr;
          Co[(size_t)m * ldc + n] = acc[i][j][r];
        }
  }
}

// ---------------------------------------------------------------------------
// One block per token: reduce Tp over 8 z-slices into LDS, then
// out[t,d] = sum_{z<4} F2p[z][t,d] (bf16) + b2[d] + Ts0·B2s[e0][d] + Ts1·B2s[e1][d].
// ---------------------------------------------------------------------------
__global__ __launch_bounds__(256) void k_final(
    const u16* __restrict__ F2p, const float* __restrict__ b2,
    const u16* __restrict__ B2s, const float* __restrict__ Tp,
    const int* __restrict__ sel, float* __restrict__ out) {
  const int t = blockIdx.x;
  const int tid = threadIdx.x;
  __shared__ float Ts[32];  // [pair 2][r 16]
  if (tid < 32) {
    int p = 2 * t + (tid >> 4);
    int r = tid & 15;
    float s = 0.f;
#pragma unroll
    for (int z = 0; z < 8; ++z) s += Tp[(size_t)z * 65536 + p * 16 + r];
    Ts[tid] = s;
  }
  __syncthreads();
  const int e0 = sel[2 * t], e1 = sel[2 * t + 1];
  const int d0 = tid * 4;
  const size_t base = (size_t)t * 1024 + d0;
  float sum[4];
  {
    float4 bb = *(const float4*)&b2[d0];
    sum[0] = bb.x; sum[1] = bb.y; sum[2] = bb.z; sum[3] = bb.w;
  }
#pragma unroll
  for (int z = 0; z < 4; ++z) {
    uint2 q = *(const uint2*)&F2p[(size_t)z * 2097152 + base];
    sum[0] += __uint_as_float(q.x << 16);
    sum[1] += __uint_as_float(q.x & 0xFFFF0000u);
    sum[2] += __uint_as_float(q.y << 16);
    sum[3] += __uint_as_float(q.y & 0xFFFF0000u);
  }
#pragma unroll
  for (int j = 0; j < 4; ++j) {
    int d = d0 + j;
    float f0[16], f1[16];
    load16bf(B2s + (size_t)e0 * 16384 + d * 16, f0);
    load16bf(B2s + (size_t)e1 * 16384 + d * 16, f1);
#pragma unroll
    for (int r = 0; r < 16; ++r)
      sum[j] += Ts[r] * f0[r] + Ts[16 + r] * f1[r];
  }
  float4 o = {sum[0], sum[1], sum[2], sum[3]};
  *(float4*)&out[base] = o;
}

// ---------------------------------------------------------------------------
extern "C" void kernel_launch(void* const* d_in, const int* in_sizes, int n_in,
                              void* d_out, int out_size, void* d_ws, size_t ws_size,
                              hipStream_t stream) {
  const float* hs   = (const float*)d_in[0];
  const float* gate = (const float*)d_in[1];
  const float* W1   = (const float*)d_in[2];
  const float* b1   = (const float*)d_in[3];
  const float* W2   = (const float*)d_in[4];
  const float* b2   = (const float*)d_in[5];
  const float* A1   = (const float*)d_in[6];
  const float* B1   = (const float*)d_in[7];
  const float* A2   = (const float*)d_in[8];
  const float* B2   = (const float*)d_in[9];

  char* ws = (char*)d_ws;
  size_t off = 0;
  auto alloc = [&](size_t bytes) -> void* {
    void* p = ws + off;
    off += (bytes + 255) & ~(size_t)255;
    return p;
  };
  u16*   Xbf  = (u16*)alloc(2097152ull * 2);        // x bf16 [2048,1024]
  u16*   W1bf = (u16*)alloc(4194304ull * 2);        // [4096,1024]
  u16*   W2bf = (u16*)alloc(4194304ull * 2);        // [1024,4096]
  u16*   B1s  = (u16*)alloc(524288ull * 2);         // 2*B1 [E,4096,16]
  u16*   B2s  = (u16*)alloc(131072ull * 2);         // 2*B2 [E,1024,16]
  u16*   A2bf = (u16*)alloc(524288ull * 2);         // A2 [E,16,4096] bf16
  float* LXp  = (float*)alloc(4ull * 262144 * 4);   // 4 k-slices of X@A1^T (4MB)
  u16*   am   = (u16*)alloc(2048ull * 4096 * 2);    // combined activation (16MB)
  u16*   Zw   = (u16*)alloc(4096ull * 4096 * 2);    // per-slot w*silu (32MB)
  u16*   F2p  = (u16*)alloc(4ull * 2097152 * 2);    // bf16 split-K partials (16MB)
  float* Tp   = (float*)alloc(8ull * 65536 * 4);    // 8 T k-split partials (2MB)
  int*   sel  = (int*)alloc(2048ull * 2 * 4);
  float* wgt  = (float*)alloc(2048ull * 2 * 4);
  int*   rows = (int*)alloc(4608 * 4);
  int*   tile_expert = (int*)alloc(72 * 4);

  // 1: cvt + router + LX (self-converting MFMA blocks)
  k_prep<<<6272, 256, 0, stream>>>(hs, gate, W1, W2, A1, B1, B2, A2,
                                   Xbf, W1bf, W2bf, B1s, B2s, A2bf,
                                   LXp, sel, wgt);
  // 2: GEMM1 = X @ W1^T with fused LoRA1+silu epilogue -> Zw, am; sort at y==32
  gemm_bt<<<dim3(16, 33, 1), 256, 0, stream>>>(
      Xbf, W1bf, nullptr, 1024, 0, 1024, 0, 0, b1, 1,
      sel, wgt, rows, tile_expert, LXp, B1s, am, Zw, nullptr, nullptr);
  // 3: GEMM2 = am @ W2^T (split-K=4, bf16 partials); T-GEMM rides y in [8,17)
  gemm_bt<<<dim3(16, 17, 4), 256, 0, stream>>>(
      am, W2bf, (void*)F2p, 4096, 1024, 1024, 2097152, 1, nullptr, 2,
      nullptr, nullptr, rows, tile_expert, nullptr, nullptr, nullptr, Zw,
      A2bf, Tp);
  // 4: out = sum F2p + b2 + (reduced Tp)·B2^T
  k_final<<<2048, 256, 0, stream>>>(F2p, b2, B2s, Tp, sel, (float*)d_out);
}

// Round 11
// 228.411 us; speedup vs baseline: 1.1357x; 1.0017x over previous
//
#include <hip/hip_runtime.h>
#include <hip/hip_bf16.h>
#include <stdint.h>

typedef unsigned short u16;
typedef unsigned int u32;

using bf16x8 = __attribute__((ext_vector_type(8))) __bf16;  // 4 VGPRs: MFMA A/B operand
using f32x4  = __attribute__((ext_vector_type(4))) float;   // MFMA C/D operand

#define AS1 __attribute__((address_space(1)))
#define AS3 __attribute__((address_space(3)))

// fp32 -> bf16 round-to-nearest-even
__device__ __forceinline__ u16 f2bf(float x) {
  u32 u = __float_as_uint(x);
  u = (u + 0x7FFFu + ((u >> 16) & 1u)) >> 16;
  return (u16)u;
}
__device__ __forceinline__ float bf2f(u32 bits) { return __uint_as_float(bits << 16); }

// async global->LDS, 16B per lane. LDS dest = wave-uniform base + lane*16.
__device__ __forceinline__ void gload16(const void* g, void* l) {
  __builtin_amdgcn_global_load_lds((AS1 void*)(const_cast<void*>(g)),
                                   (AS3 void*)l, 16, 0, 0);
}

// load 16 contiguous bf16 (32B, aligned) into 16 floats
__device__ __forceinline__ void load16bf(const u16* p, float* f) {
  uint4 a = *(const uint4*)(p);
  uint4 b = *(const uint4*)(p + 8);
  u32 v[8] = {a.x, a.y, a.z, a.w, b.x, b.y, b.z, b.w};
#pragma unroll
  for (int i = 0; i < 8; ++i) {
    f[2 * i]     = __uint_as_float(v[i] << 16);
    f[2 * i + 1] = __uint_as_float(v[i] & 0xFFFF0000u);
  }
}

// convert 8 fp32 (aligned) -> 8 bf16, one uint4 store (16B/lane)
__device__ __forceinline__ void cvt8(const float* __restrict__ s,
                                     u16* __restrict__ d, size_t i,
                                     float scale) {
  float4 a = *(const float4*)(s + i);
  float4 b = *(const float4*)(s + i + 4);
  uint4 o;
  o.x = (u32)f2bf(a.x * scale) | ((u32)f2bf(a.y * scale) << 16);
  o.y = (u32)f2bf(a.z * scale) | ((u32)f2bf(a.w * scale) << 16);
  o.z = (u32)f2bf(b.x * scale) | ((u32)f2bf(b.y * scale) << 16);
  o.w = (u32)f2bf(b.z * scale) | ((u32)f2bf(b.w * scale) << 16);
  *(uint4*)(d + i) = o;
}

__device__ __forceinline__ uint4 pack8(float4 a, float4 b) {
  uint4 o;
  o.x = (u32)f2bf(a.x) | ((u32)f2bf(a.y) << 16);
  o.y = (u32)f2bf(a.z) | ((u32)f2bf(a.w) << 16);
  o.z = (u32)f2bf(b.x) | ((u32)f2bf(b.y) << 16);
  o.w = (u32)f2bf(b.z) | ((u32)f2bf(b.w) << 16);
  return o;
}

// ---------------------------------------------------------------------------
// k_prep: blocks [0,5696) = vectorized bf16 repack (8 elems/thread).
// Blocks [5696,6208) = router. Blocks [6208,6272) = LXp = X@A1^T via MFMA.
// ---------------------------------------------------------------------------
__global__ __launch_bounds__(256) void k_prep(
    const float* __restrict__ hs, const float* __restrict__ gate,
    const float* __restrict__ W1, const float* __restrict__ W2,
    const float* __restrict__ A1, const float* __restrict__ B1,
    const float* __restrict__ B2, const float* __restrict__ A2,
    u16* __restrict__ Xbf, u16* __restrict__ W1bf, u16* __restrict__ W2bf,
    u16* __restrict__ B1s, u16* __restrict__ B2s, u16* __restrict__ A2bf,
    float* __restrict__ LXp, int* __restrict__ sel, float* __restrict__ wgt) {
  __shared__ alignas(16) u16 lsA[8192];
  __shared__ alignas(16) u16 lsB[8192];
  const int b = blockIdx.x;
  const int tid = threadIdx.x;
  if (b < 5696) {
    size_t i = ((size_t)b * 256 + tid) * 8;
    if (i < 2097152) { cvt8(hs, Xbf, i, 1.f); return; }
    i -= 2097152;
    if (i < 4194304) { cvt8(W1, W1bf, i, 1.f); return; }
    i -= 4194304;
    if (i < 4194304) { cvt8(W2, W2bf, i, 1.f); return; }
    i -= 4194304;
    if (i < 524288) { cvt8(B1, B1s, i, 2.0f); return; }   // [E,H,R], LORA_SCALE
    i -= 524288;
    if (i < 131072) { cvt8(B2, B2s, i, 2.0f); return; }   // [E,D,R], LORA_SCALE
    i -= 131072;
    cvt8(A2, A2bf, i, 1.f);                               // [E,R,H] plain
    return;
  }
  const int lane = tid & 63;
  const int wv = tid >> 6;
  if (b < 6208) {
    // ---- router: top-2 renormalized softmax = sigmoid(l0-l1) ----
    const int t = (b - 5696) * 4 + wv;
    const float* xp = hs + (size_t)t * 1024 + lane * 16;
    float4 xv[4];
#pragma unroll
    for (int i = 0; i < 4; ++i) xv[i] = *(const float4*)(xp + i * 4);
    float acc[8];
#pragma unroll
    for (int e = 0; e < 8; ++e) {
      const float* gp = gate + e * 1024 + lane * 16;
      float s = 0.f;
#pragma unroll
      for (int i = 0; i < 4; ++i) {
        float4 g = *(const float4*)(gp + i * 4);
        s += xv[i].x * g.x + xv[i].y * g.y + xv[i].z * g.z + xv[i].w * g.w;
      }
      acc[e] = s;
    }
#pragma unroll
    for (int e = 0; e < 8; ++e)
      for (int off = 32; off > 0; off >>= 1) acc[e] += __shfl_xor(acc[e], off);
    if (lane == 0) {
      int e0 = 0; float l0 = acc[0];
#pragma unroll
      for (int e = 1; e < 8; ++e) if (acc[e] > l0) { l0 = acc[e]; e0 = e; }
      int e1 = (e0 == 0) ? 1 : 0; float l1 = acc[e1];
#pragma unroll
      for (int e = 0; e < 8; ++e)
        if (e != e0 && acc[e] > l1) { l1 = acc[e]; e1 = e; }
      float p = 1.f / (1.f + __expf(l1 - l0));
      sel[2 * t] = e0; sel[2 * t + 1] = e1;
      wgt[2 * t] = p;  wgt[2 * t + 1] = 1.f - p;
    }
    return;
  }
  // ---- LX blocks: 16 t-tiles x 4 k-slices of 256 ----
  const int idx = b - 6208;
  const int tt = idx >> 2, z = idx & 3;
  const int m0 = tt * 128;
  const int k00 = z * 256;
  const int w = wv;
  const int wm = w & 1, wn = w >> 1;
  const int sr = lane >> 3, sc = lane & 7, cg = sc ^ sr;
  const int fr = lane & 15, fq = lane >> 4;
  f32x4 acc[4][4] = {};
  for (int kt = 0; kt < 256; kt += 64) {
#pragma unroll
    for (int j = 0; j < 4; ++j) {
      int row = w * 32 + sr + j * 8;
      const float* xs = hs + (size_t)(m0 + row) * 1024 + k00 + kt + cg * 8;
      *(uint4*)&lsA[row * 64 + sc * 8] =
          pack8(*(const float4*)xs, *(const float4*)(xs + 4));
      const float* as2 = A1 + (size_t)row * 1024 + k00 + kt + cg * 8;
      *(uint4*)&lsB[row * 64 + sc * 8] =
          pack8(*(const float4*)as2, *(const float4*)(as2 + 4));
    }
    __syncthreads();
#pragma unroll
    for (int s = 0; s < 2; ++s) {
      const int cl = (s * 4 + fq) ^ (fr & 7);
      bf16x8 av[4], bv[4];
#pragma unroll
      for (int i = 0; i < 4; ++i)
        av[i] = *(const bf16x8*)&lsA[(wm * 64 + i * 16 + fr) * 64 + cl * 8];
#pragma unroll
      for (int j = 0; j < 4; ++j)
        bv[j] = *(const bf16x8*)&lsB[(wn * 64 + j * 16 + fr) * 64 + cl * 8];
#pragma unroll
      for (int i = 0; i < 4; ++i)
#pragma unroll
        for (int j = 0; j < 4; ++j)
          acc[i][j] = __builtin_amdgcn_mfma_f32_16x16x32_bf16(av[i], bv[j], acc[i][j], 0, 0, 0);
    }
    __syncthreads();
  }
  float* Co = LXp + (size_t)z * 262144;
#pragma unroll
  for (int i = 0; i < 4; ++i)
#pragma unroll
    for (int j = 0; j < 4; ++j)
#pragma unroll
      for (int r = 0; r < 4; ++r) {
        int m = m0 + wm * 64 + i * 16 + fq * 4 + r;
        int n = wn * 64 + j * 16 + fr;
        Co[(size_t)m * 128 + n] = acc[i][j][r];
      }
}

// ---------------------------------------------------------------------------
// GEMM1 fused: C = X@W1^T (128x128 tile, BK=64) with MFMA-based LoRA1 epilogue.
// y<32: gemm + epilogue -> Zw[2t], Zw[2t+1], am. y==32 (x==0): expert sort.
// Epilogue: per slot s, build lxE[t][e*16+r] (expanded LX, XOR-swizzled chunks
// in the reused K-loop LDS), delta = lxE @ B1all^T via 64 MFMAs (B-frags read
// straight from global B1s, L2-resident). dacc aligns element-for-element
// with acc (same fragment geometry). ~1.5K VALU ops/thread vs 10K in R10.
// ---------------------------------------------------------------------------
__global__ __launch_bounds__(256, 2) void gemm1_fused(
    const u16* __restrict__ A, const u16* __restrict__ B,
    const float* __restrict__ bias, const int* __restrict__ sel,
    const float* __restrict__ wgt, int* __restrict__ rows,
    int* __restrict__ tile_expert, const float* __restrict__ LXp,
    const u16* __restrict__ B1s, u16* __restrict__ am, u16* __restrict__ Zw) {
  __shared__ alignas(16) u16 ls[16384];  // K-loop tiles; reused as lxE in epilogue
  u16* lsA = ls;
  u16* lsB = ls + 8192;
  const int tid = threadIdx.x;
  const int lane = tid & 63;
  const int w = tid >> 6;

  if (blockIdx.y == 32) {
    if (blockIdx.x != 0) return;
    // ---- deterministic 8-bin sort of 4096 (token,slot) pairs, 4 waves ----
    int* wavehist = (int*)ls;    // [4][8]
    int* stot = wavehist + 32;   // [8]
    int* waveoff = stot + 8;     // [4][8]
    for (int i = tid; i < 4608; i += 256) rows[i] = -1;
    int ev[16], rk[16];
    int wc[8] = {};
    const unsigned long long ltmask = (1ull << lane) - 1;
#pragma unroll
    for (int j = 0; j < 16; ++j) {
      ev[j] = sel[w * 1024 + j * 64 + lane];
#pragma unroll
      for (int ex = 0; ex < 8; ++ex) {
        unsigned long long m = __ballot(ev[j] == ex);
        if (ev[j] == ex) rk[j] = wc[ex] + __popcll(m & ltmask);
        wc[ex] += __popcll(m);
      }
    }
#pragma unroll
    for (int ex = 0; ex < 8; ++ex)
      if (lane == ex) wavehist[w * 8 + ex] = wc[ex];  // wc wave-uniform
    __syncthreads();
    if (tid < 8) {
      int s = 0;
      for (int ww = 0; ww < 4; ++ww) s += wavehist[ww * 8 + tid];
      stot[tid] = s;
    }
    __syncthreads();
    if (tid < 32) {
      int ww = tid >> 3, ex = tid & 7;
      int base = 0;
      for (int e2 = 0; e2 < ex; ++e2) base += (stot[e2] + 63) & ~63;
      for (int w2 = 0; w2 < ww; ++w2) base += wavehist[w2 * 8 + ex];
      waveoff[ww * 8 + ex] = base;
    } else if (tid < 104) {
      int tt = tid - 32;
      int pos = tt * 64, acc2 = 0, e2 = 0;
      while (e2 < 7) {
        int na = acc2 + ((stot[e2] + 63) & ~63);
        if (pos < na) break;
        acc2 = na; ++e2;
      }
      tile_expert[tt] = e2;
    }
    __syncthreads();
#pragma unroll
    for (int j = 0; j < 16; ++j)
      rows[waveoff[w * 8 + ev[j]] + rk[j]] = w * 1024 + j * 64 + lane;
    return;
  }

  const int m0 = blockIdx.x * 128;
  const int n0 = blockIdx.y * 128;
  const int wm = w & 1, wn = w >> 1;
  const int K = 1024;

  f32x4 acc[4][4] = {};

  const int sr = lane >> 3;
  const int sc = lane & 7;
  const int cg = sc ^ sr;
  const u16* Ag = A + (size_t)(m0 + w * 32 + sr) * K + cg * 8;
  const u16* Bg = B + (size_t)(n0 + w * 32 + sr) * K + cg * 8;
  u16* lA = lsA + w * 2048;
  u16* lB = lsB + w * 2048;

  const int fr = lane & 15;
  const int fq = lane >> 4;

  for (int kt = 0; kt < K; kt += 64) {
#pragma unroll
    for (int j = 0; j < 4; ++j) {
      gload16(Ag + (size_t)j * 8 * K, lA + j * 512);
      gload16(Bg + (size_t)j * 8 * K, lB + j * 512);
    }
    Ag += 64; Bg += 64;
    __syncthreads();
#pragma unroll
    for (int s = 0; s < 2; ++s) {
      const int cl = (s * 4 + fq) ^ (fr & 7);
      bf16x8 av[4], bv[4];
#pragma unroll
      for (int i = 0; i < 4; ++i)
        av[i] = *(const bf16x8*)&lsA[(wm * 64 + i * 16 + fr) * 64 + cl * 8];
#pragma unroll
      for (int j = 0; j < 4; ++j)
        bv[j] = *(const bf16x8*)&lsB[(wn * 64 + j * 16 + fr) * 64 + cl * 8];
#pragma unroll
      for (int i = 0; i < 4; ++i)
#pragma unroll
        for (int j = 0; j < 4; ++j)
          acc[i][j] = __builtin_amdgcn_mfma_f32_16x16x32_bf16(av[i], bv[j], acc[i][j], 0, 0, 0);
    }
    __syncthreads();
  }

  // ======== MFMA-based LoRA1 + silu epilogue ========
  u16* lxE = ls;  // [128 rows][16 chunks of 8 u16], chunk XOR-swizzled by row&7
  float b1v[4];
#pragma unroll
  for (int j = 0; j < 4; ++j) b1v[j] = bias[n0 + wn * 64 + j * 16 + fr];
  u32 s0p[4][4][2];  // slot-0 results, packed bf16 pairs (r even|odd)

#pragma unroll
  for (int s = 0; s < 2; ++s) {
    // zero lxE (2048 uint4)
#pragma unroll
    for (int q = 0; q < 8; ++q)
      *(uint4*)&lxE[(q * 256 + tid) * 8] = make_uint4(0, 0, 0, 0);
    __syncthreads();
    // scatter: token m, half of rank-range; lx = 4-slice sum of LXp
    {
      int m = tid >> 1, half = tid & 1;
      int e = sel[(m0 + m) * 2 + s];
      const float* src = LXp + (size_t)(m0 + m) * 128 + e * 16 + half * 8;
      float4 a = {0.f, 0.f, 0.f, 0.f}, b = {0.f, 0.f, 0.f, 0.f};
#pragma unroll
      for (int zz = 0; zz < 4; ++zz) {
        float4 va = *(const float4*)(src + zz * 262144);
        float4 vb = *(const float4*)(src + zz * 262144 + 4);
        a.x += va.x; a.y += va.y; a.z += va.z; a.w += va.w;
        b.x += vb.x; b.y += vb.y; b.z += vb.z; b.w += vb.w;
      }
      int chunk = (e * 2 + half) ^ (m & 7);
      *(uint4*)&lxE[m * 128 + chunk * 8] = pack8(a, b);
    }
    __syncthreads();
    // delta = lxE @ B1all^T (K=128), B-frags straight from global B1s
    f32x4 dacc[4][4] = {};
#pragma unroll
    for (int kk = 0; kk < 4; ++kk) {
      bf16x8 av[4], bv[4];
      const int c = kk * 4 + fq;
#pragma unroll
      for (int i = 0; i < 4; ++i) {
        int tr = wm * 64 + i * 16 + fr;
        int ph = c ^ (tr & 7);
        av[i] = *(const bf16x8*)&lxE[tr * 128 + ph * 8];
      }
#pragma unroll
      for (int j = 0; j < 4; ++j) {
        int n = n0 + wn * 64 + j * 16 + fr;
        bv[j] = *(const bf16x8*)&B1s[(size_t)(c >> 1) * 65536 + (size_t)n * 16 + (c & 1) * 8];
      }
#pragma unroll
      for (int i = 0; i < 4; ++i)
#pragma unroll
        for (int j = 0; j < 4; ++j)
          dacc[i][j] = __builtin_amdgcn_mfma_f32_16x16x32_bf16(av[i], bv[j], dacc[i][j], 0, 0, 0);
    }
    __syncthreads();  // lxE reads done before next pass's zero
    // elementwise: silu + weight; store Zw row; pass1 also stores am
#pragma unroll
    for (int i = 0; i < 4; ++i)
#pragma unroll
      for (int r = 0; r < 4; ++r) {
        int mt2 = wm * 64 + i * 16 + fq * 4 + r;
        int t = m0 + mt2;
        float wv = wgt[t * 2 + s];
#pragma unroll
        for (int j = 0; j < 4; ++j) {
          int nn = wn * 64 + j * 16 + fr;
          float cv = acc[i][j][r] + b1v[j];
          float z = cv + dacc[i][j][r];
          float sv = wv * z / (1.f + __expf(-z));
          Zw[(size_t)(2 * t + s) * 4096 + n0 + nn] = f2bf(sv);
          if (s == 0) {
            if (r & 1) s0p[i][j][r >> 1] |= (u32)f2bf(sv) << 16;
            else       s0p[i][j][r >> 1]  = (u32)f2bf(sv);
          } else {
            u32 pk = s0p[i][j][r >> 1];
            float s0v = bf2f((r & 1) ? (pk >> 16) : (pk & 0xFFFFu));
            am[(size_t)t * 4096 + n0 + nn] = f2bf(s0v + sv);
          }
        }
      }
  }
}

// ---------------------------------------------------------------------------
// GEMM2: F2p[z] = am @ W2^T (128x128 tile, split-K=4, bf16 partials).
// y<8: gemm. y>=8: T-GEMM Tp[zz][p,:] = Zw[p, k-split zz of 512] @ A2[e]^T.
// ---------------------------------------------------------------------------
__global__ __launch_bounds__(256, 2) void gemm2k(
    const u16* __restrict__ A, const u16* __restrict__ B, u16* __restrict__ Cv,
    const int* __restrict__ rows, const int* __restrict__ tile_expert,
    const u16* __restrict__ Zw, const u16* __restrict__ A2bf,
    float* __restrict__ Tp) {
  __shared__ alignas(16) u16 lsA[8192];
  __shared__ alignas(16) u16 lsB[8192];
  const int tid = threadIdx.x;
  const int lane = tid & 63;
  const int w = tid >> 6;

  if (blockIdx.y >= 8) {
    // ---- T-GEMM: tile of 64 sorted rows, zz = k-split of 512 (8 slices) ----
    const int idx = (blockIdx.y - 8) * 16 + blockIdx.x;  // 0..143
    const int tile = idx >> 1;                            // 0..71
    const int zz = (idx & 1) * 4 + blockIdx.z;            // 0..7
    const int k0 = zz * 512;
    const int fr = lane & 15, fq = lane >> 4;
    const int e = tile_expert[tile];
    int p = rows[tile * 64 + w * 16 + fr];
    int p0 = p < 0 ? 0 : p;
    const u16* zp = Zw + (size_t)p0 * 4096 + k0 + fq * 8;
    const u16* ap = A2bf + (size_t)e * 65536 + (size_t)fr * 4096 + k0 + fq * 8;
    f32x4 acc = {};
#pragma unroll
    for (int k = 0; k < 512; k += 32) {
      bf16x8 av = *(const bf16x8*)(zp + k);
      bf16x8 bv = *(const bf16x8*)(ap + k);
      acc = __builtin_amdgcn_mfma_f32_16x16x32_bf16(av, bv, acc, 0, 0, 0);
    }
#pragma unroll
    for (int r = 0; r < 4; ++r) {
      int pm = rows[tile * 64 + w * 16 + fq * 4 + r];
      if (pm >= 0) Tp[(size_t)zz * 65536 + pm * 16 + fr] = acc[r];
    }
    return;
  }

  const int m0 = blockIdx.x * 128;
  const int n0 = blockIdx.y * 128;
  const int z = blockIdx.z;
  const int wm = w & 1, wn = w >> 1;
  const int K = 4096, Ksub = 1024;

  f32x4 acc[4][4] = {};

  const int sr = lane >> 3;
  const int sc = lane & 7;
  const int cg = sc ^ sr;
  const u16* Ag = A + (size_t)(m0 + w * 32 + sr) * K + (size_t)z * Ksub + cg * 8;
  const u16* Bg = B + (size_t)(n0 + w * 32 + sr) * K + (size_t)z * Ksub + cg * 8;
  u16* lA = lsA + w * 2048;
  u16* lB = lsB + w * 2048;

  const int fr = lane & 15;
  const int fq = lane >> 4;

  for (int kt = 0; kt < Ksub; kt += 64) {
#pragma unroll
    for (int j = 0; j < 4; ++j) {
      gload16(Ag + (size_t)j * 8 * K, lA + j * 512);
      gload16(Bg + (size_t)j * 8 * K, lB + j * 512);
    }
    Ag += 64; Bg += 64;
    __syncthreads();
#pragma unroll
    for (int s = 0; s < 2; ++s) {
      const int cl = (s * 4 + fq) ^ (fr & 7);
      bf16x8 av[4], bv[4];
#pragma unroll
      for (int i = 0; i < 4; ++i)
        av[i] = *(const bf16x8*)&lsA[(wm * 64 + i * 16 + fr) * 64 + cl * 8];
#pragma unroll
      for (int j = 0; j < 4; ++j)
        bv[j] = *(const bf16x8*)&lsB[(wn * 64 + j * 16 + fr) * 64 + cl * 8];
#pragma unroll
      for (int i = 0; i < 4; ++i)
#pragma unroll
        for (int j = 0; j < 4; ++j)
          acc[i][j] = __builtin_amdgcn_mfma_f32_16x16x32_bf16(av[i], bv[j], acc[i][j], 0, 0, 0);
    }
    __syncthreads();
  }

  u16* Co = Cv + (size_t)z * 2097152;
#pragma unroll
  for (int i = 0; i < 4; ++i)
#pragma unroll
    for (int j = 0; j < 4; ++j)
#pragma unroll
      for (int r = 0; r < 4; ++r) {
        int m = m0 + wm * 64 + i * 16 + fq * 4 + r;
        int n = n0 + wn * 64 + j * 16 + fr;
        Co[(size_t)m * 1024 + n] = f2bf(acc[i][j][r]);
      }
}

// ---------------------------------------------------------------------------
// One block per token: reduce Tp over 8 z-slices into LDS, then
// out[t,d] = sum_{z<4} F2p[z][t,d] (bf16) + b2[d] + Ts0·B2s[e0][d] + Ts1·B2s[e1][d].
// ---------------------------------------------------------------------------
__global__ __launch_bounds__(256) void k_final(
    const u16* __restrict__ F2p, const float* __restrict__ b2,
    const u16* __restrict__ B2s, const float* __restrict__ Tp,
    const int* __restrict__ sel, float* __restrict__ out) {
  const int t = blockIdx.x;
  const int tid = threadIdx.x;
  __shared__ float Ts[32];  // [pair 2][r 16]
  if (tid < 32) {
    int p = 2 * t + (tid >> 4);
    int r = tid & 15;
    float s = 0.f;
#pragma unroll
    for (int z = 0; z < 8; ++z) s += Tp[(size_t)z * 65536 + p * 16 + r];
    Ts[tid] = s;
  }
  __syncthreads();
  const int e0 = sel[2 * t], e1 = sel[2 * t + 1];
  const int d0 = tid * 4;
  const size_t base = (size_t)t * 1024 + d0;
  float sum[4];
  {
    float4 bb = *(const float4*)&b2[d0];
    sum[0] = bb.x; sum[1] = bb.y; sum[2] = bb.z; sum[3] = bb.w;
  }
#pragma unroll
  for (int z = 0; z < 4; ++z) {
    uint2 q = *(const uint2*)&F2p[(size_t)z * 2097152 + base];
    sum[0] += __uint_as_float(q.x << 16);
    sum[1] += __uint_as_float(q.x & 0xFFFF0000u);
    sum[2] += __uint_as_float(q.y << 16);
    sum[3] += __uint_as_float(q.y & 0xFFFF0000u);
  }
#pragma unroll
  for (int j = 0; j < 4; ++j) {
    int d = d0 + j;
    float f0[16], f1[16];
    load16bf(B2s + (size_t)e0 * 16384 + d * 16, f0);
    load16bf(B2s + (size_t)e1 * 16384 + d * 16, f1);
#pragma unroll
    for (int r = 0; r < 16; ++r)
      sum[j] += Ts[r] * f0[r] + Ts[16 + r] * f1[r];
  }
  float4 o = {sum[0], sum[1], sum[2], sum[3]};
  *(float4*)&out[base] = o;
}

// ---------------------------------------------------------------------------
extern "C" void kernel_launch(void* const* d_in, const int* in_sizes, int n_in,
                              void* d_out, int out_size, void* d_ws, size_t ws_size,
                              hipStream_t stream) {
  const float* hs   = (const float*)d_in[0];
  const float* gate = (const float*)d_in[1];
  const float* W1   = (const float*)d_in[2];
  const float* b1   = (const float*)d_in[3];
  const float* W2   = (const float*)d_in[4];
  const float* b2   = (const float*)d_in[5];
  const float* A1   = (const float*)d_in[6];
  const float* B1   = (const float*)d_in[7];
  const float* A2   = (const float*)d_in[8];
  const float* B2   = (const float*)d_in[9];

  char* ws = (char*)d_ws;
  size_t off = 0;
  auto alloc = [&](size_t bytes) -> void* {
    void* p = ws + off;
    off += (bytes + 255) & ~(size_t)255;
    return p;
  };
  u16*   Xbf  = (u16*)alloc(2097152ull * 2);        // x bf16 [2048,1024]
  u16*   W1bf = (u16*)alloc(4194304ull * 2);        // [4096,1024]
  u16*   W2bf = (u16*)alloc(4194304ull * 2);        // [1024,4096]
  u16*   B1s  = (u16*)alloc(524288ull * 2);         // 2*B1 [E,4096,16]
  u16*   B2s  = (u16*)alloc(131072ull * 2);         // 2*B2 [E,1024,16]
  u16*   A2bf = (u16*)alloc(524288ull * 2);         // A2 [E,16,4096] bf16
  float* LXp  = (float*)alloc(4ull * 262144 * 4);   // 4 k-slices of X@A1^T (4MB)
  u16*   am   = (u16*)alloc(2048ull * 4096 * 2);    // combined activation (16MB)
  u16*   Zw   = (u16*)alloc(4096ull * 4096 * 2);    // per-slot w*silu (32MB)
  u16*   F2p  = (u16*)alloc(4ull * 2097152 * 2);    // bf16 split-K partials (16MB)
  float* Tp   = (float*)alloc(8ull * 65536 * 4);    // 8 T k-split partials (2MB)
  int*   sel  = (int*)alloc(2048ull * 2 * 4);
  float* wgt  = (float*)alloc(2048ull * 2 * 4);
  int*   rows = (int*)alloc(4608 * 4);
  int*   tile_expert = (int*)alloc(72 * 4);

  // 1: cvt + router + LX (self-converting MFMA blocks)
  k_prep<<<6272, 256, 0, stream>>>(hs, gate, W1, W2, A1, B1, B2, A2,
                                   Xbf, W1bf, W2bf, B1s, B2s, A2bf,
                                   LXp, sel, wgt);
  // 2: GEMM1 = X @ W1^T with MFMA LoRA1+silu epilogue -> Zw, am; sort at y==32
  gemm1_fused<<<dim3(16, 33), 256, 0, stream>>>(
      Xbf, W1bf, b1, sel, wgt, rows, tile_expert, LXp, B1s, am, Zw);
  // 3: GEMM2 = am @ W2^T (split-K=4, bf16 partials); T-GEMM rides y in [8,17)
  gemm2k<<<dim3(16, 17, 4), 256, 0, stream>>>(
      am, W2bf, F2p, rows, tile_expert, Zw, A2bf, Tp);
  // 4: out = sum F2p + b2 + (reduced Tp)·B2^T
  k_final<<<2048, 256, 0, stream>>>(F2p, b2, B2s, Tp, sel, (float*)d_out);
}